// Round 2
// baseline (72.693 us; speedup 1.0000x reference)
//
#include <hip/hip_runtime.h>

// Fused shift-conv: per-block-m fusion.
//   conv1: t4[k(8), o(4), m, n(28)] = sum_{i<64, j<3} w1[k,i,j] * x[i*4+o, (m+j-2) mod 28, n]
//          (tap zero when m+j==0 or m+j==29; the mod-wrap is the roll by +1 along H)
//   conv2: out[i(32), o2(8), m, n] = sum_{j<4, kk<3} w2[i,j,kk] * t4[o2, j, m, n+kk-1]
// conv2 has no taps along m, so one block per m row needs only its own t4 row -> exact fusion.
__global__ __launch_bounds__(256) void fused_shiftconv(const float* __restrict__ x,
                                                       const float* __restrict__ w1,
                                                       const float* __restrict__ w2,
                                                       float* __restrict__ out) {
    __shared__ float w1s[8 * 193];   // w1[k][192], row-padded to 193 (192%32==0 -> same-bank across k)
    __shared__ float w2s[384];       // w2[i][12]
    __shared__ float t4s[32 * 33];   // rows (k*4+o), 28 values at [1..28], zero guards at [0] and [29]

    const int tid = threadIdx.x;
    const int m = blockIdx.x;        // 0..27

    // stage weights
    for (int idx = tid; idx < 1536; idx += 256) {
        const int k = idx / 192;
        w1s[k * 193 + (idx - k * 192)] = w1[idx];
    }
    if (tid < 128) {
        w2s[tid] = w2[tid];
        w2s[tid + 128] = w2[tid + 128];
        w2s[tid + 256] = w2[tid + 256];
    }
    if (tid < 64) {                  // zero the two guard slots of each of the 32 rows
        t4s[(tid & 31) * 33 + (tid >> 5) * 29] = 0.f;
    }
    __syncthreads();

    // ---- phase 1: t4 row m into LDS ----
    if (tid < 224) {
        const int o = tid / 56;          // 0..3
        const int q = (tid >> 3) % 7;    // 0..6 (n quad)
        const int k = tid & 7;           // 0..7 -> 8 consecutive lanes share x address (broadcast)
        const float* wk = &w1s[k * 193];
        float4 acc = make_float4(0.f, 0.f, 0.f, 0.f);
#pragma unroll
        for (int j = 0; j < 3; ++j) {
            const int mj = m + j;
            if (mj == 0 || mj == 29) continue;   // zero-pad rows (uniform per block)
            int hh = mj - 2;
            if (hh < 0) hh += 28;                // roll wrap: -1 -> 27
            const float* xb = x + o * 784 + hh * 28 + q * 4;
#pragma unroll 8
            for (int i = 0; i < 64; ++i) {
                const float4 v = *reinterpret_cast<const float4*>(xb + i * 3136);
                const float w = wk[i * 3 + j];
                acc.x = fmaf(w, v.x, acc.x);
                acc.y = fmaf(w, v.y, acc.y);
                acc.z = fmaf(w, v.z, acc.z);
                acc.w = fmaf(w, v.w, acc.w);
            }
        }
        float* dst = &t4s[(k * 4 + o) * 33 + 1 + q * 4];
        dst[0] = acc.x; dst[1] = acc.y; dst[2] = acc.z; dst[3] = acc.w;
    }
    __syncthreads();

    // ---- phase 2: out row m, all 256 channels ----
    const int i2 = tid >> 3;             // 0..31
    const int o2 = tid & 7;              // 0..7
    const float* wr = &w2s[i2 * 12];
    float* orow = out + (i2 * 8 + o2) * 784 + m * 28;
#pragma unroll
    for (int q = 0; q < 7; ++q) {
        float4 r;
        float* rp = &r.x;
#pragma unroll
        for (int e = 0; e < 4; ++e) {
            const int n = q * 4 + e;
            float acc = 0.f;
#pragma unroll
            for (int j = 0; j < 4; ++j) {
                const float* trow = &t4s[(o2 * 4 + j) * 33 + n];  // [n+kk] covers guards at 0/29
#pragma unroll
                for (int kk = 0; kk < 3; ++kk) {
                    acc = fmaf(wr[j * 3 + kk], trow[kk], acc);
                }
            }
            rp[e] = acc;
        }
        *reinterpret_cast<float4*>(orow + q * 4) = r;
    }
}

extern "C" void kernel_launch(void* const* d_in, const int* in_sizes, int n_in,
                              void* d_out, int out_size, void* d_ws, size_t ws_size,
                              hipStream_t stream) {
    const float* x  = (const float*)d_in[0];   // (1,256,28,28) f32
    const float* w1 = (const float*)d_in[1];   // (8,64,3) f32
    const float* w2 = (const float*)d_in[2];   // (32,4,3) f32
    float* out = (float*)d_out;                // (1,256,28,28) f32

    fused_shiftconv<<<dim3(28), 256, 0, stream>>>(x, w1, w2, out);
}

// Round 5
// 61.740 us; speedup vs baseline: 1.1774x; 1.1774x over previous
//
#include <hip/hip_runtime.h>

// Fused shift-conv, block = (m, o2): 224 blocks, self-sufficient fusion.
//   conv1: t4[k(8), o(4), m, n(28)] = sum_{i<64, j<3} w1[k,i,j] * x[i*4+o, (m+j-2) mod 28, n]
//          (tap zero when m+j==0 or m+j==29; mod-wrap is the roll by +1 along H)
//   conv2: out[i2(32), o2(8), m, n] = sum_{j<4, kk<3} w2[i2,j,kk] * t4[o2, j, m, n+kk-1]
// conv2 channels (*, o2) at row m need only t4[o2, 0..3, m, :] -> block (m,o2) computes
// those 112 values in phase 1 (LDS), then all 32*28 outputs in phase 2.
__global__ __launch_bounds__(224) void fused_shiftconv(const float* __restrict__ x,
                                                       const float* __restrict__ w1,
                                                       const float* __restrict__ w2,
                                                       float* __restrict__ out) {
    __shared__ float w2s[384];
    __shared__ float t4s[4][32];     // 28 values at [1..28], zero guards at [0] and [29]

    const int tid = threadIdx.x;
    const int m  = blockIdx.x >> 3;  // 0..27
    const int o2 = blockIdx.x & 7;   // 0..7

    for (int idx = tid; idx < 384; idx += 224) w2s[idx] = w2[idx];
    if (tid < 8) t4s[tid >> 1][(tid & 1) * 29] = 0.f;   // guards

    // ---- phase 1: t4[o2, 0..3, m, 0..27] into LDS (112 threads) ----
    if (tid < 112) {
        const int o = tid / 28;          // 0..3 (= conv2's j)
        const int n = tid - o * 28;      // 0..27
        const float* wp = w1 + o2 * 192; // lane-uniform -> scalar loads
        float acc = 0.f;
#pragma unroll
        for (int j = 0; j < 3; ++j) {
            const int mj = m + j;
            if (mj == 0 || mj == 29) continue;   // zero-pad rows (block-uniform branch)
            int hh = mj - 2;
            if (hh < 0) hh += 28;                // roll wrap: -1 -> 27
            const float* xp = x + o * 784 + hh * 28 + n;
#pragma unroll
            for (int i = 0; i < 64; ++i) {
                acc = fmaf(wp[i * 3 + j], xp[i * 3136], acc);
            }
        }
        t4s[o][n + 1] = acc;
    }
    __syncthreads();

    // ---- phase 2: out[0..31, o2, m, 0..27] (224 threads) ----
    const int i2 = tid / 7;              // 0..31
    const int q  = tid - i2 * 7;         // 0..6 (n quad)
    const float* wr = &w2s[i2 * 12];
    float4 r;
    float* rp = &r.x;
#pragma unroll
    for (int e = 0; e < 4; ++e) {
        const int n = q * 4 + e;
        float acc = 0.f;
#pragma unroll
        for (int j = 0; j < 4; ++j) {
#pragma unroll
            for (int kk = 0; kk < 3; ++kk) {
                acc = fmaf(wr[j * 3 + kk], t4s[j][n + kk], acc);  // guards handle pad
            }
        }
        rp[e] = acc;
    }
    *reinterpret_cast<float4*>(out + (i2 * 8 + o2) * 784 + m * 28 + q * 4) = r;
}

extern "C" void kernel_launch(void* const* d_in, const int* in_sizes, int n_in,
                              void* d_out, int out_size, void* d_ws, size_t ws_size,
                              hipStream_t stream) {
    const float* x  = (const float*)d_in[0];   // (1,256,28,28) f32
    const float* w1 = (const float*)d_in[1];   // (8,64,3) f32
    const float* w2 = (const float*)d_in[2];   // (32,4,3) f32
    float* out = (float*)d_out;                // (1,256,28,28) f32

    fused_shiftconv<<<dim3(224), 224, 0, stream>>>(x, w1, w2, out);
}